// Round 3
// baseline (305.834 us; speedup 1.0000x reference)
//
#include <hip/hip_runtime.h>

// DCNv4 on gfx950 — bf16 MFMA pipeline, fragment-swizzled operands.
// R10: oms occupancy fix. LDS 135.7KB -> 53.9KB (2 blocks/CU):
//  - s_v: 20-row band window (offsets |off|<=0.1 << halo 2) instead of full
//    66x66 plane; zero-filled outside image, y-clamped to window.
//  - s_om: bf16 with 16B-chunk XOR swizzle (chunk ^ (p&3)) -> bank-balanced
//    for 8B writes and 16B reads (f32 64KB version had slot conflicts).
//  - sampler inner loop: bf16->f32 via bit-shift + packed v_pk_fma_f32
//    (float2 elementwise_fma) instead of 32 cvt + 32 scalar fma per k.
// KW: vp/op frag-swizzle + per-g padded om_wG
// KF: dwconv3x3 + value GEMM (block = image row) -> xdwF, value_g
// OMS: om GEMM + bilinear sampling -> sampledF (frag layout)
// K4: out = sampledF @ op_wF (M=64, fp32 NHWC out)

typedef __bf16 bf16_t;
typedef bf16_t bf16x8 __attribute__((ext_vector_type(8)));
typedef bf16_t bf16x4 __attribute__((ext_vector_type(4)));
typedef float f32x4 __attribute__((ext_vector_type(4)));
typedef float f32x2 __attribute__((ext_vector_type(2)));
typedef unsigned int u32x4 __attribute__((ext_vector_type(4)));

namespace {
constexpr int NN = 8, HH = 64, WW = 64, CC = 256;
constexpr int G = 32, GC = 8;
constexpr int NPIX = NN * HH * WW;            // 32768
}

// fragment-swizzled flat index for a [rows][256] bf16 matrix
__device__ __forceinline__ size_t fragIdx(int row, int c) {
  return ((size_t)(row >> 4) * 4096) + ((c >> 5) * 512) + (((c >> 3) & 3) * 128) +
         ((row & 15) * 8) + (c & 7);
}

// ---------------- KW: weights -> bf16 fragment layouts ----------------------
// b<16: vp_w  b<32: op_w  (64x64 LDS transpose, as before)
// b>=32: om_wG[g] = per-g fragment matrix [32 rows(j, 27 real)][256 cols(c)]
__global__ __launch_bounds__(256) void convert_weights_kernel(
    const float* __restrict__ om_w, const float* __restrict__ vp_w,
    const float* __restrict__ op_w, bf16_t* __restrict__ om_wG,
    bf16_t* __restrict__ vp_wF, bf16_t* __restrict__ op_wF) {
  __shared__ float s_t[64][65];
  __shared__ float s_w[256][27];
  const int b = blockIdx.x, t = threadIdx.x;
  if (b < 32) {
    const float* src;
    bf16_t* dst;
    int kt, nt;
    if (b < 16) { src = vp_w; dst = vp_wF; kt = b >> 2; nt = b & 3; }
    else        { src = op_w; dst = op_wF; kt = (b - 16) >> 2; nt = (b - 16) & 3; }
    const int nl = t & 63, kh = t >> 6;
    const int n = nt * 64 + nl;
#pragma unroll
    for (int i = 0; i < 16; ++i) {
      const int kl = kh * 16 + i;
      s_t[kl][nl] = src[(size_t)(kt * 64 + kl) * CC + n];
    }
    __syncthreads();
    const int lane = t & 63, kq = lane >> 4, n15 = lane & 15, n16 = t >> 6;
#pragma unroll
    for (int it = 0; it < 2; ++it) {
      bf16x8 v;
#pragma unroll
      for (int j = 0; j < 8; ++j)
        v[j] = (bf16_t)s_t[it * 32 + kq * 8 + j][n16 * 16 + n15];
      const size_t off = (size_t)(nt * 4 + n16) * 4096 + (size_t)(kt * 2 + it) * 512 +
                         kq * 128 + n15 * 8;
      *(bf16x8*)(dst + off) = v;
    }
  } else {
    const int g = b - 32;
    // transpose load: s_w[c][j] = om_w[c][g*27+j]
#pragma unroll
    for (int j = 0; j < 27; ++j) s_w[t][j] = om_w[(size_t)t * 864 + g * 27 + j];
    __syncthreads();
#pragma unroll
    for (int i = 0; i < 4; ++i) {
      const int chunk = i * 256 + t;  // 1024 chunks of 8 bf16
      const int tile = chunk >> 9, ks = (chunk >> 6) & 7, kq = (chunk >> 4) & 3,
                n15 = chunk & 15;
      const int j = tile * 16 + n15;
      bf16x8 v;
#pragma unroll
      for (int cl = 0; cl < 8; ++cl) {
        const int c = ks * 32 + kq * 8 + cl;
        v[cl] = (j < 27) ? (bf16_t)s_w[c][j] : (bf16_t)0.0f;
      }
      *(bf16x8*)(om_wG + ((size_t)g << 13) + (size_t)chunk * 8) = v;
    }
  }
}

// ---------------- KF: fused dwconv3x3 + value GEMM; block = one image row ----
__global__ __launch_bounds__(512, 4) void dwconv_value_kernel(
    const float* __restrict__ x, const float* __restrict__ dw_w,
    const float* __restrict__ dw_b, const bf16_t* __restrict__ vp_wF,
    const float* __restrict__ vp_b, bf16_t* __restrict__ xdwF,
    bf16_t* __restrict__ value_g) {
  __shared__ bf16_t s_xf[64 * 256];  // x bf16 fragments for this row's 4 m-tiles

  const int t = threadIdx.x;
  const int row = blockIdx.x;        // img*64 + y
  const int y = row & 63;
  const int img = row >> 6;

  // ---- Phase A: dwconv
  {
    const int cq = (t & 63) * 4;   // channel base
    const int seg = t >> 6;        // 8-px segment
    const bool up = (y > 0), dn = (y < HH - 1);
    const float* xrow = x + (size_t)row * WW * CC + cq;

    const float4 bias = *(const float4*)&dw_b[cq];
    float4 dw[9];
#pragma unroll
    for (int i = 0; i < 9; ++i) dw[i] = *(const float4*)&dw_w[(size_t)i * CC + cq];

    const float4 zero = make_float4(0.f, 0.f, 0.f, 0.f);
    auto loadcol = [&](int xx, float4 c[3]) {
      if (xx < 0 || xx >= WW) { c[0] = c[1] = c[2] = zero; return; }
      c[0] = up ? *(const float4*)(xrow + ((size_t)xx - WW) * CC) : zero;
      c[1] = *(const float4*)(xrow + (size_t)xx * CC);
      c[2] = dn ? *(const float4*)(xrow + ((size_t)xx + WW) * CC) : zero;
    };

    const int x0 = seg * 8;
    float4 cm[3], cc[3], cp[3];
    loadcol(x0 - 1, cm);
    loadcol(x0, cc);

    for (int xx = x0; xx < x0 + 8; ++xx) {
      loadcol(xx + 1, cp);
      float4 a = bias;
#pragma unroll
      for (int r = 0; r < 3; ++r) {
        const float4 w0 = dw[r * 3 + 0], w1 = dw[r * 3 + 1], w2 = dw[r * 3 + 2];
        a.x = fmaf(cm[r].x, w0.x, fmaf(cc[r].x, w1.x, fmaf(cp[r].x, w2.x, a.x)));
        a.y = fmaf(cm[r].y, w0.y, fmaf(cc[r].y, w1.y, fmaf(cp[r].y, w2.y, a.y)));
        a.z = fmaf(cm[r].z, w0.z, fmaf(cc[r].z, w1.z, fmaf(cp[r].z, w2.z, a.z)));
        a.w = fmaf(cm[r].w, w0.w, fmaf(cc[r].w, w1.w, fmaf(cp[r].w, w2.w, a.w)));
      }
      const int pix = row * WW + xx;
      bf16x4 av, cv;
      av[0] = (bf16_t)a.x; av[1] = (bf16_t)a.y; av[2] = (bf16_t)a.z; av[3] = (bf16_t)a.w;
      cv[0] = (bf16_t)cc[1].x; cv[1] = (bf16_t)cc[1].y;
      cv[2] = (bf16_t)cc[1].z; cv[3] = (bf16_t)cc[1].w;
      *(bf16x4*)&xdwF[fragIdx(pix, cq)] = av;
      const int lf = (xx >> 4) * 4096 + ((cq >> 5) * 512) + (((cq >> 3) & 3) * 128) +
                     ((xx & 15) * 8) + (cq & 7);
      *(bf16x4*)&s_xf[lf] = cv;
#pragma unroll
      for (int r = 0; r < 3; ++r) { cm[r] = cc[r]; cc[r] = cp[r]; }
    }
  }
  __syncthreads();

  // ---- Phase B: value GEMM (M=64 from LDS, N=256)
  {
    const int lane = t & 63;
    const int wave = t >> 6;
    const int mq = wave >> 1;      // m-tile 0..3
    const int nh = wave & 1;       // n-half
    const int m = lane & 15;
    const int kq = lane >> 4;

    const bf16_t* Ap = s_xf + mq * 4096 + lane * 8;
    const bf16_t* Bp = vp_wF + (size_t)(nh * 8) * 4096 + lane * 8;

    f32x4 acc[8] = {};
#pragma unroll
    for (int ks = 0; ks < 8; ++ks) {
      const bf16x8 a = *(const bf16x8*)(Ap + ks * 512);
#pragma unroll
      for (int i = 0; i < 8; ++i) {
        const bf16x8 b = *(const bf16x8*)(Bp + (size_t)i * 4096 + ks * 512);
        acc[i] = __builtin_amdgcn_mfma_f32_16x16x32_bf16(a, b, acc[i], 0, 0, 0);
      }
    }

#pragma unroll
    for (int i = 0; i < 8; ++i) {
      const int n = (nh * 8 + i) * 16 + m;
      const float bs = vp_b[n];
      const int g = n >> 3, c = n & 7;
      bf16_t* plane = value_g + ((size_t)(img * G + g) << 15) + c;
#pragma unroll
      for (int r = 0; r < 4; ++r) {
        const int pl = mq * 16 + kq * 4 + r;           // pixel local 0..63
        const int pin = y * 64 + pl;                   // pixel within image
        plane[(size_t)pin * GC] = (bf16_t)(acc[i][r] + bs);
      }
    }
  }
}

// ---------------- OMS: fused om GEMM + sampling; block = (img, g, band) -----
// grid b: img = b&7 (XCD affinity), g = (b>>3)&31, band (16 rows) = b>>8
__global__ __launch_bounds__(512, 4) void oms_kernel(
    const bf16_t* __restrict__ xdwF, const bf16_t* __restrict__ om_wG,
    const float* __restrict__ om_b, const bf16_t* __restrict__ value_g,
    bf16_t* __restrict__ sampledF) {
  __shared__ bf16x8 s_v[20 * 66];        // 21,120 B band window (rows y0-2..y0+17)
  __shared__ bf16_t s_om[8][64][32];     // 32,768 B per-wave om tile (chunk-swz)

  const int t = threadIdx.x;
  const int lane = t & 63, wave = t >> 6;
  const int b = blockIdx.x;
  const int img = b & 7, g = (b >> 3) & 31, quarter = b >> 8;
  const int c15 = lane & 15, kq = lane >> 4;
  const int tile0 = img * 256 + quarter * 64;   // global px-tile base
  const int y0 = quarter * 16;                  // first image row of band

  // ---- B-frags (g's padded 32 om columns) into registers; reused 8x each
  bf16x8 wf[2][8];
  {
    const bf16_t* base = om_wG + ((size_t)g << 13) + (size_t)lane * 8;
#pragma unroll
    for (int n2 = 0; n2 < 2; ++n2)
#pragma unroll
      for (int ks = 0; ks < 8; ++ks)
        wf[n2][ks] = *(const bf16x8*)(base + n2 * 4096 + ks * 512);
  }
  float bias[2][4];
#pragma unroll
  for (int n2 = 0; n2 < 2; ++n2)
#pragma unroll
    for (int r = 0; r < 4; ++r) {
      const int j = n2 * 16 + kq * 4 + r;
      bias[n2][r] = (j < 27) ? om_b[g * 27 + j] : 0.0f;
    }

  // ---- stage band window: rows y0-2..y0+17, cols -1..64, zero outside image
  {
    const bf16x8 zv = {};
    const bf16x8* plane = (const bf16x8*)(value_g + ((size_t)(img * G + g) << 15));
    for (int i = t; i < 20 * 66; i += 512) {
      const int wr = i / 66;
      const int cx = i - wr * 66;
      const int yr = y0 - 2 + wr;
      bf16x8 v = zv;
      if (yr >= 0 && yr < HH && cx >= 1 && cx <= 64) v = plane[yr * 64 + cx - 1];
      s_v[i] = v;
    }
  }

  // ---- om GEMM for one 4-tile group -> per-wave s_om (D[j][pix], bf16, swz)
  auto do_mfma = [&](const int grp) {
    const int tb = tile0 + wave * 8 + grp * 4;
#pragma unroll
    for (int q = 0; q < 4; ++q) {
      const bf16_t* Ap = xdwF + ((size_t)(tb + q)) * 4096 + (size_t)lane * 8;
      f32x4 a0 = {}, a1 = {};
#pragma unroll
      for (int ks = 0; ks < 8; ++ks) {
        const bf16x8 xf = *(const bf16x8*)(Ap + ks * 512);
        a0 = __builtin_amdgcn_mfma_f32_16x16x32_bf16(wf[0][ks], xf, a0, 0, 0, 0);
        a1 = __builtin_amdgcn_mfma_f32_16x16x32_bf16(wf[1][ks], xf, a1, 0, 0, 0);
      }
      // lane holds j = n2*16 + kq*4 + r for pixel p = q*16 + c15
      const int p = q * 16 + c15;
      const int pk = p & 3;
      bf16_t* rowp = &s_om[wave][p][0];
      bf16x4 b0, b1;
#pragma unroll
      for (int r = 0; r < 4; ++r) {
        b0[r] = (bf16_t)(a0[r] + bias[0][r]);
        b1[r] = (bf16_t)(a1[r] + bias[1][r]);
      }
      const int h = (kq & 1) * 4;
      *(bf16x4*)(rowp + (((kq >> 1) ^ pk) << 3) + h) = b0;
      *(bf16x4*)(rowp + (((2 + (kq >> 1)) ^ pk) << 3) + h) = b1;
    }
  };

  // ---- sampling: lane <-> one pixel of the wave's 64-px group
  auto do_sample = [&](const int grp) {
    const int pin = quarter * 1024 + wave * 128 + grp * 64 + lane;  // in-image px
    const bf16_t* rowp = &s_om[wave][lane][0];
    const int key3 = lane & 3;
    float arr[32];
#pragma unroll
    for (int c = 0; c < 4; ++c) {
      const bf16x8 o = *(const bf16x8*)(rowp + ((c ^ key3) << 3));
#pragma unroll
      for (int j = 0; j < 8; ++j) arr[c * 8 + j] = (float)o[j];
    }
    const int xw = pin & 63, y = pin >> 6;

    f32x2 acc2[4] = {};
#pragma unroll
    for (int k = 0; k < 9; ++k) {
      const float pxf = (float)(xw + (k % 3) - 1) + arr[2 * k];
      const float pyf = (float)(y + (k / 3) - 1) + arr[2 * k + 1];
      const float mk = arr[18 + k];
      const float x0f = floorf(pxf), y0f = floorf(pyf);
      const float tx = pxf - x0f, ty = pyf - y0f;
      const int ix = (int)x0f, iy = (int)y0f;

      // x: clamp to padded [-1,64]; y: clamp to band window [0,19]
      const int iX0 = min(max(ix, -1), 64) + 1;
      const int iX1 = min(max(ix + 1, -1), 64) + 1;
      const int riy = iy - y0 + 2;
      const int iY0 = min(max(riy, 0), 19);
      const int iY1 = min(max(riy + 1, 0), 19);

      const u32x4 c00 = *(const u32x4*)&s_v[iY0 * 66 + iX0];
      const u32x4 c01 = *(const u32x4*)&s_v[iY0 * 66 + iX1];
      const u32x4 c10 = *(const u32x4*)&s_v[iY1 * 66 + iX0];
      const u32x4 c11 = *(const u32x4*)&s_v[iY1 * 66 + iX1];

      const float w00 = mk * (1.0f - ty) * (1.0f - tx);
      const float w01 = mk * (1.0f - ty) * tx;
      const float w10 = mk * ty * (1.0f - tx);
      const float w11 = mk * ty * tx;
      const f32x2 W00 = {w00, w00}, W01 = {w01, w01};
      const f32x2 W10 = {w10, w10}, W11 = {w11, w11};

#pragma unroll
      for (int pr = 0; pr < 4; ++pr) {
        f32x2 v;
        v[0] = __builtin_bit_cast(float, c00[pr] << 16);
        v[1] = __builtin_bit_cast(float, c00[pr] & 0xffff0000u);
        acc2[pr] = __builtin_elementwise_fma(W00, v, acc2[pr]);
        v[0] = __builtin_bit_cast(float, c01[pr] << 16);
        v[1] = __builtin_bit_cast(float, c01[pr] & 0xffff0000u);
        acc2[pr] = __builtin_elementwise_fma(W01, v, acc2[pr]);
        v[0] = __builtin_bit_cast(float, c10[pr] << 16);
        v[1] = __builtin_bit_cast(float, c10[pr] & 0xffff0000u);
        acc2[pr] = __builtin_elementwise_fma(W10, v, acc2[pr]);
        v[0] = __builtin_bit_cast(float, c11[pr] << 16);
        v[1] = __builtin_bit_cast(float, c11[pr] & 0xffff0000u);
        acc2[pr] = __builtin_elementwise_fma(W11, v, acc2[pr]);
      }
    }

    bf16x8 sv;
#pragma unroll
    for (int pr = 0; pr < 4; ++pr) {
      sv[2 * pr] = (bf16_t)acc2[pr][0];
      sv[2 * pr + 1] = (bf16_t)acc2[pr][1];
    }
    *(bf16x8*)(sampledF + fragIdx(img * 4096 + pin, g * 8)) = sv;
  };

  do_mfma(0);          // overlaps with staging loads
  __syncthreads();     // s_v ready
  do_sample(0);
  do_mfma(1);
  do_sample(1);
}

// ---------------- K4: out = sampledF @ op_wF, M=64/block, fp32 NHWC ----------
__global__ __launch_bounds__(512, 4) void out_gemm_kernel(
    const bf16_t* __restrict__ AF, const bf16_t* __restrict__ BF,
    float* __restrict__ out) {
  const int lane = threadIdx.x & 63;
  const int wave = threadIdx.x >> 6;
  const int mq = wave >> 1;
  const int nh = wave & 1;
  const int mt = blockIdx.x * 4 + mq;
  const int m = lane & 15;
  const int kq = lane >> 4;

  const bf16_t* Ap = AF + (size_t)mt * 4096 + lane * 8;
  const bf16_t* Bp = BF + (size_t)(nh * 8) * 4096 + lane * 8;

  f32x4 acc[8] = {};
#pragma unroll
  for (int ks = 0; ks < 8; ++ks) {
    const bf16x8 a = *(const bf16x8*)(Ap + ks * 512);
#pragma unroll
    for (int i = 0; i < 8; ++i) {
      const bf16x8 b = *(const bf16x8*)(Bp + (size_t)i * 4096 + ks * 512);
      acc[i] = __builtin_amdgcn_mfma_f32_16x16x32_bf16(a, b, acc[i], 0, 0, 0);
    }
  }

#pragma unroll
  for (int i = 0; i < 8; ++i) {
    const int n = (nh * 8 + i) * 16 + m;
#pragma unroll
    for (int r = 0; r < 4; ++r) {
      const int pix = mt * 16 + kq * 4 + r;
      out[(size_t)pix * CC + n] = acc[i][r];
    }
  }
}

extern "C" void kernel_launch(void* const* d_in, const int* in_sizes, int n_in,
                              void* d_out, int out_size, void* d_ws, size_t ws_size,
                              hipStream_t stream) {
  const float* x = (const float*)d_in[0];
  const float* dw_w = (const float*)d_in[1];
  const float* dw_b = (const float*)d_in[2];
  const float* om_w = (const float*)d_in[3];
  const float* om_b = (const float*)d_in[4];
  const float* vp_w = (const float*)d_in[5];
  const float* vp_b = (const float*)d_in[6];
  const float* op_w = (const float*)d_in[7];
  float* out = (float*)d_out;

  // workspace layout (bytes)
  char* ws = (char*)d_ws;
  bf16_t* value_g = (bf16_t*)ws;                      // 16,777,216
  bf16_t* xdwF = (bf16_t*)(ws + 16777216);            // 16,777,216
  bf16_t* sampledF = (bf16_t*)(ws + 33554432);        // 16,777,216
  bf16_t* om_wG = (bf16_t*)(ws + 50331648);           //    524,288
  bf16_t* vp_wF = (bf16_t*)(ws + 50855936);           //    131,072
  bf16_t* op_wF = (bf16_t*)(ws + 50987008);           //    131,072

  convert_weights_kernel<<<64, 256, 0, stream>>>(om_w, vp_w, op_w,
                                                 om_wG, vp_wF, op_wF);
  dwconv_value_kernel<<<NN * HH, 512, 0, stream>>>(x, dw_w, dw_b, vp_wF, vp_b,
                                                   xdwF, value_g);
  oms_kernel<<<1024, 512, 0, stream>>>(xdwF, om_wG, om_b, value_g, sampledF);
  out_gemm_kernel<<<NPIX / 64, 512, 0, stream>>>(sampledF, op_wF, out);
}

// Round 4
// 245.825 us; speedup vs baseline: 1.2441x; 1.2441x over previous
//
#include <hip/hip_runtime.h>

// DCNv4 on gfx950 — bf16 MFMA pipeline, fragment-swizzled operands.
// R11: oms rebuild.
//  - grid b = img*128 + quarter*32 + g: blocks sharing the xdwF quarter-slice
//    are contiguous -> L2 reuse robust to chunked OR round-robin XCD dispatch
//    (R10's img=b&7 relied on round-robin; FETCH exploded 18.5->183 MB).
//  - s_om deleted: 4x4 register shuffle-transpose (shfl_xor 16/32 butterfly)
//    gives each lane its pixel's 32 om values; kills the 5.1M-cycle LDS
//    conflicts and 32 KB of LDS.
//  - LDS = 21 KB band window only -> 2 blocks/CU (launch_bounds(512,4)).
// KW: vp/op frag-swizzle + per-g padded om_wG
// KF: dwconv3x3 + value GEMM (block = image row) -> xdwF, value_g
// OMS: om GEMM (B in regs) + shuffle transpose + bilinear sampling -> sampledF
// K4: out = sampledF @ op_wF (M=64, fp32 NHWC out)

typedef __bf16 bf16_t;
typedef bf16_t bf16x8 __attribute__((ext_vector_type(8)));
typedef bf16_t bf16x4 __attribute__((ext_vector_type(4)));
typedef float f32x4 __attribute__((ext_vector_type(4)));
typedef float f32x2 __attribute__((ext_vector_type(2)));
typedef unsigned int u32x4 __attribute__((ext_vector_type(4)));
typedef unsigned int u32x2 __attribute__((ext_vector_type(2)));

namespace {
constexpr int NN = 8, HH = 64, WW = 64, CC = 256;
constexpr int G = 32, GC = 8;
constexpr int NPIX = NN * HH * WW;            // 32768
}

// fragment-swizzled flat index for a [rows][256] bf16 matrix
__device__ __forceinline__ size_t fragIdx(int row, int c) {
  return ((size_t)(row >> 4) * 4096) + ((c >> 5) * 512) + (((c >> 3) & 3) * 128) +
         ((row & 15) * 8) + (c & 7);
}

__device__ __forceinline__ float bf2f_lo(unsigned u) {
  return __builtin_bit_cast(float, u << 16);
}
__device__ __forceinline__ float bf2f_hi(unsigned u) {
  return __builtin_bit_cast(float, u & 0xffff0000u);
}

// ---------------- KW: weights -> bf16 fragment layouts ----------------------
// b<16: vp_w  b<32: op_w  (64x64 LDS transpose, as before)
// b>=32: om_wG[g] = per-g fragment matrix [32 rows(j, 27 real)][256 cols(c)]
__global__ __launch_bounds__(256) void convert_weights_kernel(
    const float* __restrict__ om_w, const float* __restrict__ vp_w,
    const float* __restrict__ op_w, bf16_t* __restrict__ om_wG,
    bf16_t* __restrict__ vp_wF, bf16_t* __restrict__ op_wF) {
  __shared__ float s_t[64][65];
  __shared__ float s_w[256][27];
  const int b = blockIdx.x, t = threadIdx.x;
  if (b < 32) {
    const float* src;
    bf16_t* dst;
    int kt, nt;
    if (b < 16) { src = vp_w; dst = vp_wF; kt = b >> 2; nt = b & 3; }
    else        { src = op_w; dst = op_wF; kt = (b - 16) >> 2; nt = (b - 16) & 3; }
    const int nl = t & 63, kh = t >> 6;
    const int n = nt * 64 + nl;
#pragma unroll
    for (int i = 0; i < 16; ++i) {
      const int kl = kh * 16 + i;
      s_t[kl][nl] = src[(size_t)(kt * 64 + kl) * CC + n];
    }
    __syncthreads();
    const int lane = t & 63, kq = lane >> 4, n15 = lane & 15, n16 = t >> 6;
#pragma unroll
    for (int it = 0; it < 2; ++it) {
      bf16x8 v;
#pragma unroll
      for (int j = 0; j < 8; ++j)
        v[j] = (bf16_t)s_t[it * 32 + kq * 8 + j][n16 * 16 + n15];
      const size_t off = (size_t)(nt * 4 + n16) * 4096 + (size_t)(kt * 2 + it) * 512 +
                         kq * 128 + n15 * 8;
      *(bf16x8*)(dst + off) = v;
    }
  } else {
    const int g = b - 32;
    // transpose load: s_w[c][j] = om_w[c][g*27+j]
#pragma unroll
    for (int j = 0; j < 27; ++j) s_w[t][j] = om_w[(size_t)t * 864 + g * 27 + j];
    __syncthreads();
#pragma unroll
    for (int i = 0; i < 4; ++i) {
      const int chunk = i * 256 + t;  // 1024 chunks of 8 bf16
      const int tile = chunk >> 9, ks = (chunk >> 6) & 7, kq = (chunk >> 4) & 3,
                n15 = chunk & 15;
      const int j = tile * 16 + n15;
      bf16x8 v;
#pragma unroll
      for (int cl = 0; cl < 8; ++cl) {
        const int c = ks * 32 + kq * 8 + cl;
        v[cl] = (j < 27) ? (bf16_t)s_w[c][j] : (bf16_t)0.0f;
      }
      *(bf16x8*)(om_wG + ((size_t)g << 13) + (size_t)chunk * 8) = v;
    }
  }
}

// ---------------- KF: fused dwconv3x3 + value GEMM; block = one image row ----
__global__ __launch_bounds__(512, 4) void dwconv_value_kernel(
    const float* __restrict__ x, const float* __restrict__ dw_w,
    const float* __restrict__ dw_b, const bf16_t* __restrict__ vp_wF,
    const float* __restrict__ vp_b, bf16_t* __restrict__ xdwF,
    bf16_t* __restrict__ value_g) {
  __shared__ bf16_t s_xf[64 * 256];  // x bf16 fragments for this row's 4 m-tiles

  const int t = threadIdx.x;
  const int row = blockIdx.x;        // img*64 + y
  const int y = row & 63;
  const int img = row >> 6;

  // ---- Phase A: dwconv
  {
    const int cq = (t & 63) * 4;   // channel base
    const int seg = t >> 6;        // 8-px segment
    const bool up = (y > 0), dn = (y < HH - 1);
    const float* xrow = x + (size_t)row * WW * CC + cq;

    const float4 bias = *(const float4*)&dw_b[cq];
    float4 dw[9];
#pragma unroll
    for (int i = 0; i < 9; ++i) dw[i] = *(const float4*)&dw_w[(size_t)i * CC + cq];

    const float4 zero = make_float4(0.f, 0.f, 0.f, 0.f);
    auto loadcol = [&](int xx, float4 c[3]) {
      if (xx < 0 || xx >= WW) { c[0] = c[1] = c[2] = zero; return; }
      c[0] = up ? *(const float4*)(xrow + ((size_t)xx - WW) * CC) : zero;
      c[1] = *(const float4*)(xrow + (size_t)xx * CC);
      c[2] = dn ? *(const float4*)(xrow + ((size_t)xx + WW) * CC) : zero;
    };

    const int x0 = seg * 8;
    float4 cm[3], cc[3], cp[3];
    loadcol(x0 - 1, cm);
    loadcol(x0, cc);

    for (int xx = x0; xx < x0 + 8; ++xx) {
      loadcol(xx + 1, cp);
      float4 a = bias;
#pragma unroll
      for (int r = 0; r < 3; ++r) {
        const float4 w0 = dw[r * 3 + 0], w1 = dw[r * 3 + 1], w2 = dw[r * 3 + 2];
        a.x = fmaf(cm[r].x, w0.x, fmaf(cc[r].x, w1.x, fmaf(cp[r].x, w2.x, a.x)));
        a.y = fmaf(cm[r].y, w0.y, fmaf(cc[r].y, w1.y, fmaf(cp[r].y, w2.y, a.y)));
        a.z = fmaf(cm[r].z, w0.z, fmaf(cc[r].z, w1.z, fmaf(cp[r].z, w2.z, a.z)));
        a.w = fmaf(cm[r].w, w0.w, fmaf(cc[r].w, w1.w, fmaf(cp[r].w, w2.w, a.w)));
      }
      const int pix = row * WW + xx;
      bf16x4 av, cv;
      av[0] = (bf16_t)a.x; av[1] = (bf16_t)a.y; av[2] = (bf16_t)a.z; av[3] = (bf16_t)a.w;
      cv[0] = (bf16_t)cc[1].x; cv[1] = (bf16_t)cc[1].y;
      cv[2] = (bf16_t)cc[1].z; cv[3] = (bf16_t)cc[1].w;
      *(bf16x4*)&xdwF[fragIdx(pix, cq)] = av;
      const int lf = (xx >> 4) * 4096 + ((cq >> 5) * 512) + (((cq >> 3) & 3) * 128) +
                     ((xx & 15) * 8) + (cq & 7);
      *(bf16x4*)&s_xf[lf] = cv;
#pragma unroll
      for (int r = 0; r < 3; ++r) { cm[r] = cc[r]; cc[r] = cp[r]; }
    }
  }
  __syncthreads();

  // ---- Phase B: value GEMM (M=64 from LDS, N=256)
  {
    const int lane = t & 63;
    const int wave = t >> 6;
    const int mq = wave >> 1;      // m-tile 0..3
    const int nh = wave & 1;       // n-half
    const int m = lane & 15;
    const int kq = lane >> 4;

    const bf16_t* Ap = s_xf + mq * 4096 + lane * 8;
    const bf16_t* Bp = vp_wF + (size_t)(nh * 8) * 4096 + lane * 8;

    f32x4 acc[8] = {};
#pragma unroll
    for (int ks = 0; ks < 8; ++ks) {
      const bf16x8 a = *(const bf16x8*)(Ap + ks * 512);
#pragma unroll
      for (int i = 0; i < 8; ++i) {
        const bf16x8 b = *(const bf16x8*)(Bp + (size_t)i * 4096 + ks * 512);
        acc[i] = __builtin_amdgcn_mfma_f32_16x16x32_bf16(a, b, acc[i], 0, 0, 0);
      }
    }

#pragma unroll
    for (int i = 0; i < 8; ++i) {
      const int n = (nh * 8 + i) * 16 + m;
      const float bs = vp_b[n];
      const int g = n >> 3, c = n & 7;
      bf16_t* plane = value_g + ((size_t)(img * G + g) << 15) + c;
#pragma unroll
      for (int r = 0; r < 4; ++r) {
        const int pl = mq * 16 + kq * 4 + r;           // pixel local 0..63
        const int pin = y * 64 + pl;                   // pixel within image
        plane[(size_t)pin * GC] = (bf16_t)(acc[i][r] + bs);
      }
    }
  }
}

// ---------------- OMS: fused om GEMM + sampling; block = (img, quarter, g) --
// b = img*128 + quarter*32 + g  (g in low bits: the 32 blocks sharing one
// xdwF quarter-slice are contiguous -> co-resident under any XCD mapping)
__global__ __launch_bounds__(512, 4) void oms_kernel(
    const bf16_t* __restrict__ xdwF, const bf16_t* __restrict__ om_wG,
    const float* __restrict__ om_b, const bf16_t* __restrict__ value_g,
    bf16_t* __restrict__ sampledF) {
  __shared__ bf16x8 s_v[20 * 66];        // 21,120 B band window (rows y0-2..y0+17)

  const int t = threadIdx.x;
  const int lane = t & 63, wave = t >> 6;
  const int b = blockIdx.x;
  const int img = b >> 7, quarter = (b >> 5) & 3, g = b & 31;
  const int c15 = lane & 15, kq = lane >> 4;
  const int k0 = kq & 1, k1 = kq >> 1;
  const int tile0 = img * 256 + quarter * 64;   // global px-tile base
  const int y0 = quarter * 16;                  // first image row of band

  // ---- B-frags (g's padded 32 om columns) into registers; reused 8x each
  bf16x8 wf[2][8];
  {
    const bf16_t* base = om_wG + ((size_t)g << 13) + (size_t)lane * 8;
#pragma unroll
    for (int n2 = 0; n2 < 2; ++n2)
#pragma unroll
      for (int ks = 0; ks < 8; ++ks)
        wf[n2][ks] = *(const bf16x8*)(base + n2 * 4096 + ks * 512);
  }
  float bias[2][4];
#pragma unroll
  for (int n2 = 0; n2 < 2; ++n2)
#pragma unroll
    for (int r = 0; r < 4; ++r) {
      const int j = n2 * 16 + kq * 4 + r;
      bias[n2][r] = (j < 27) ? om_b[g * 27 + j] : 0.0f;
    }

  // ---- stage band window: rows y0-2..y0+17, cols -1..64, zero outside image
  {
    const bf16x8 zv = {};
    const bf16x8* plane = (const bf16x8*)(value_g + ((size_t)(img * G + g) << 15));
    for (int i = t; i < 20 * 66; i += 512) {
      const int wr = i / 66;
      const int cx = i - wr * 66;
      const int yr = y0 - 2 + wr;
      bf16x8 v = zv;
      if (yr >= 0 && yr < HH && cx >= 1 && cx <= 64) v = plane[yr * 64 + cx - 1];
      s_v[i] = v;
    }
  }

  // ---- om GEMM for 4 tiles + 4x4 lane-group shuffle transpose -> F[slot]
  // After transpose: lane l holds ALL 32 om j's of pixel (grp-local) p = l,
  // packed bf16: F[m] = {j 4m..4m+3 (2 u32), j 16+4m..16+4m+3 (2 u32)}.
  unsigned F[4][4];
  auto do_mfma = [&](const int grp) {
    unsigned D[4][4];
    const int tb = tile0 + wave * 8 + grp * 4;
#pragma unroll
    for (int q = 0; q < 4; ++q) {
      const bf16_t* Ap = xdwF + ((size_t)(tb + q)) * 4096 + (size_t)lane * 8;
      f32x4 a0 = {}, a1 = {};
#pragma unroll
      for (int ks = 0; ks < 8; ++ks) {
        const bf16x8 xf = *(const bf16x8*)(Ap + ks * 512);
        a0 = __builtin_amdgcn_mfma_f32_16x16x32_bf16(wf[0][ks], xf, a0, 0, 0, 0);
        a1 = __builtin_amdgcn_mfma_f32_16x16x32_bf16(wf[1][ks], xf, a1, 0, 0, 0);
      }
      bf16x4 p0, p1;
#pragma unroll
      for (int r = 0; r < 4; ++r) {
        p0[r] = (bf16_t)(a0[r] + bias[0][r]);
        p1[r] = (bf16_t)(a1[r] + bias[1][r]);
      }
      const u32x2 d0 = __builtin_bit_cast(u32x2, p0);
      const u32x2 d1 = __builtin_bit_cast(u32x2, p1);
      D[q][0] = d0[0]; D[q][1] = d0[1];
      D[q][2] = d1[0]; D[q][3] = d1[1];
    }
    // butterfly round 1: lane^16 (kq bit 0)
    unsigned E[4][4];
#pragma unroll
    for (int qh = 0; qh < 2; ++qh) {
      const int qe = qh * 2, qo = qe + 1;
#pragma unroll
      for (int s = 0; s < 4; ++s) {
        const unsigned te = __shfl_xor(D[qe][s], 16, 64);
        const unsigned to = __shfl_xor(D[qo][s], 16, 64);
        E[qe][s] = k0 ? to : D[qe][s];
        E[qo][s] = k0 ? D[qo][s] : te;
      }
    }
    // butterfly round 2: lane^32 (kq bit 1)
#pragma unroll
    for (int ql = 0; ql < 2; ++ql) {
      const int qa = ql, qb = ql + 2;
#pragma unroll
      for (int s = 0; s < 4; ++s) {
        const unsigned ta = __shfl_xor(E[qa][s], 32, 64);
        const unsigned tb2 = __shfl_xor(E[qb][s], 32, 64);
        F[qa][s] = k1 ? tb2 : E[qa][s];
        F[qb][s] = k1 ? E[qb][s] : ta;
      }
    }
  };

  // ---- sampling: lane <-> one pixel of the wave's 64-px group
  auto do_sample = [&](const int grp) {
    const int pin = quarter * 1024 + wave * 128 + grp * 64 + lane;  // in-image px
    float arr[27];
#pragma unroll
    for (int m = 0; m < 4; ++m)
#pragma unroll
      for (int e = 0; e < 4; ++e) {
        const int j = 4 * m + e;
        const unsigned u = F[m][e >> 1];
        arr[j] = (e & 1) ? bf2f_hi(u) : bf2f_lo(u);
        if (16 + j < 27) {
          const unsigned u2 = F[m][2 + (e >> 1)];
          arr[16 + j] = (e & 1) ? bf2f_hi(u2) : bf2f_lo(u2);
        }
      }
    const int xw = pin & 63, y = pin >> 6;

    f32x2 acc2[4] = {};
#pragma unroll
    for (int k = 0; k < 9; ++k) {
      const float pxf = (float)(xw + (k % 3) - 1) + arr[2 * k];
      const float pyf = (float)(y + (k / 3) - 1) + arr[2 * k + 1];
      const float mk = arr[18 + k];
      const float x0f = floorf(pxf), y0f = floorf(pyf);
      const float tx = pxf - x0f, ty = pyf - y0f;
      const int ix = (int)x0f, iy = (int)y0f;

      // x: clamp to padded [-1,64]; y: clamp to band window [0,19]
      const int iX0 = min(max(ix, -1), 64) + 1;
      const int iX1 = min(max(ix + 1, -1), 64) + 1;
      const int riy = iy - y0 + 2;
      const int iY0 = min(max(riy, 0), 19);
      const int iY1 = min(max(riy + 1, 0), 19);

      const u32x4 c00 = *(const u32x4*)&s_v[iY0 * 66 + iX0];
      const u32x4 c01 = *(const u32x4*)&s_v[iY0 * 66 + iX1];
      const u32x4 c10 = *(const u32x4*)&s_v[iY1 * 66 + iX0];
      const u32x4 c11 = *(const u32x4*)&s_v[iY1 * 66 + iX1];

      const float w00 = mk * (1.0f - ty) * (1.0f - tx);
      const float w01 = mk * (1.0f - ty) * tx;
      const float w10 = mk * ty * (1.0f - tx);
      const float w11 = mk * ty * tx;
      const f32x2 W00 = {w00, w00}, W01 = {w01, w01};
      const f32x2 W10 = {w10, w10}, W11 = {w11, w11};

#pragma unroll
      for (int pr = 0; pr < 4; ++pr) {
        f32x2 v;
        v[0] = bf2f_lo(c00[pr]);
        v[1] = bf2f_hi(c00[pr]);
        acc2[pr] = __builtin_elementwise_fma(W00, v, acc2[pr]);
        v[0] = bf2f_lo(c01[pr]);
        v[1] = bf2f_hi(c01[pr]);
        acc2[pr] = __builtin_elementwise_fma(W01, v, acc2[pr]);
        v[0] = bf2f_lo(c10[pr]);
        v[1] = bf2f_hi(c10[pr]);
        acc2[pr] = __builtin_elementwise_fma(W10, v, acc2[pr]);
        v[0] = bf2f_lo(c11[pr]);
        v[1] = bf2f_hi(c11[pr]);
        acc2[pr] = __builtin_elementwise_fma(W11, v, acc2[pr]);
      }
    }

    bf16x8 sv;
#pragma unroll
    for (int pr = 0; pr < 4; ++pr) {
      sv[2 * pr] = (bf16_t)acc2[pr][0];
      sv[2 * pr + 1] = (bf16_t)acc2[pr][1];
    }
    *(bf16x8*)(sampledF + fragIdx(img * 4096 + pin, g * 8)) = sv;
  };

  do_mfma(0);          // overlaps with staging loads (independent of s_v)
  __syncthreads();     // s_v ready
  do_sample(0);
  do_mfma(1);
  do_sample(1);
}

// ---------------- K4: out = sampledF @ op_wF, M=64/block, fp32 NHWC ----------
__global__ __launch_bounds__(512, 4) void out_gemm_kernel(
    const bf16_t* __restrict__ AF, const bf16_t* __restrict__ BF,
    float* __restrict__ out) {
  const int lane = threadIdx.x & 63;
  const int wave = threadIdx.x >> 6;
  const int mq = wave >> 1;
  const int nh = wave & 1;
  const int mt = blockIdx.x * 4 + mq;
  const int m = lane & 15;
  const int kq = lane >> 4;

  const bf16_t* Ap = AF + (size_t)mt * 4096 + lane * 8;
  const bf16_t* Bp = BF + (size_t)(nh * 8) * 4096 + lane * 8;

  f32x4 acc[8] = {};
#pragma unroll
  for (int ks = 0; ks < 8; ++ks) {
    const bf16x8 a = *(const bf16x8*)(Ap + ks * 512);
#pragma unroll
    for (int i = 0; i < 8; ++i) {
      const bf16x8 b = *(const bf16x8*)(Bp + (size_t)i * 4096 + ks * 512);
      acc[i] = __builtin_amdgcn_mfma_f32_16x16x32_bf16(a, b, acc[i], 0, 0, 0);
    }
  }

#pragma unroll
  for (int i = 0; i < 8; ++i) {
    const int n = (nh * 8 + i) * 16 + m;
#pragma unroll
    for (int r = 0; r < 4; ++r) {
      const int pix = mt * 16 + kq * 4 + r;
      out[(size_t)pix * CC + n] = acc[i][r];
    }
  }
}

extern "C" void kernel_launch(void* const* d_in, const int* in_sizes, int n_in,
                              void* d_out, int out_size, void* d_ws, size_t ws_size,
                              hipStream_t stream) {
  const float* x = (const float*)d_in[0];
  const float* dw_w = (const float*)d_in[1];
  const float* dw_b = (const float*)d_in[2];
  const float* om_w = (const float*)d_in[3];
  const float* om_b = (const float*)d_in[4];
  const float* vp_w = (const float*)d_in[5];
  const float* vp_b = (const float*)d_in[6];
  const float* op_w = (const float*)d_in[7];
  float* out = (float*)d_out;

  // workspace layout (bytes)
  char* ws = (char*)d_ws;
  bf16_t* value_g = (bf16_t*)ws;                      // 16,777,216
  bf16_t* xdwF = (bf16_t*)(ws + 16777216);            // 16,777,216
  bf16_t* sampledF = (bf16_t*)(ws + 33554432);        // 16,777,216
  bf16_t* om_wG = (bf16_t*)(ws + 50331648);           //    524,288
  bf16_t* vp_wF = (bf16_t*)(ws + 50855936);           //    131,072
  bf16_t* op_wF = (bf16_t*)(ws + 50987008);           //    131,072

  convert_weights_kernel<<<64, 256, 0, stream>>>(om_w, vp_w, op_w,
                                                 om_wG, vp_wF, op_wF);
  dwconv_value_kernel<<<NN * HH, 512, 0, stream>>>(x, dw_w, dw_b, vp_wF, vp_b,
                                                   xdwF, value_g);
  oms_kernel<<<1024, 512, 0, stream>>>(xdwF, om_wG, om_b, value_g, sampledF);
  out_gemm_kernel<<<NPIX / 64, 512, 0, stream>>>(sampledF, op_wF, out);
}